// Round 2
// baseline (228.067 us; speedup 1.0000x reference)
//
#include <hip/hip_runtime.h>
#include <stdint.h>

#define M_DIM 4096
#define N_DIM 4096
#define K_DIM 4096
#define BM 128
#define BN 128
#define BKB 128   // K-bytes (= i8 elems) per tile
#define NT 4      // gate tiles
#define TCOLS (N_DIM / NT)   // 1024 output cols per gate tile
#define NCVT 8192            // conversion blocks (2M threads, 16 elem each)

typedef __attribute__((ext_vector_type(4)))  int     int4v;
typedef __attribute__((ext_vector_type(4)))  float   f32x4;
typedef __attribute__((ext_vector_type(16))) uint8_t u8x16;

#define XSCALE (127.0f / 4.25f)
#define XDEQ   (4.25f / 127.0f)

// ---------------- fp32 -> i8 quantizers ----------------
__device__ __forceinline__ uint8_t q8(float v) {
    float c = fminf(fmaxf(v * XSCALE, -127.0f), 127.0f);
    return (uint8_t)(int8_t)(int)__builtin_rintf(c);
}
__device__ __forceinline__ uint8_t s8(float v) {           // exact ternary sign
    return (uint8_t)(int8_t)((v > 0.0f) - (v < 0.0f));
}

// One dispatch, three roles by block id:
//   blocks [0, NCVT)      : convert 16 fp32 -> 16 i8 per thread (64B load, 16B store)
//                           + zero-fill 2 gated-off (row,tile) output pairs per block
//   blocks [NCVT, NCVT+4) : per-tile row compaction (LDS counter, no global atomics)
__global__ __launch_bounds__(256) void cvt_i8_kernel(const float* __restrict__ x,
                                                     const float* __restrict__ w,
                                                     int8_t* __restrict__ xq,
                                                     int8_t* __restrict__ wq,
                                                     const int* __restrict__ gate,
                                                     float* __restrict__ out,
                                                     int* __restrict__ rowlist,
                                                     int* __restrict__ counts) {
    const int tid = threadIdx.x;
    const int bid = blockIdx.x;

    if (bid >= NCVT) {               // ---- compaction: one block per gate tile ----
        const int t = bid - NCVT;
        __shared__ int lcnt;
        if (tid == 0) lcnt = 0;
        __syncthreads();
        const int lane = tid & 63;
        for (int i = 0; i < 16; ++i) {
            int row  = i * 256 + tid;
            int pred = (gate[row * NT + t] != 0);
            unsigned long long m = __ballot(pred);
            if (m != 0) {
                int leader = __ffsll((long long)m) - 1;
                int base = 0;
                if (lane == leader) base = atomicAdd(&lcnt, (int)__popcll(m));
                base = __shfl(base, leader);
                if (pred) {
                    int prefix = (int)__popcll(m & ((1ull << lane) - 1ull));
                    rowlist[t * M_DIM + base + prefix] = row;
                }
            }
        }
        __syncthreads();
        if (tid == 0) counts[t] = lcnt;
        return;
    }

    // ---- zero-fill: 2 (row,tile) pairs per block, 16B/thread each ----
#pragma unroll
    for (int pp = 0; pp < 2; ++pp) {
        int p   = bid * 2 + pp;
        int row = p >> 2, t = p & 3;
        if (gate[row * NT + t] == 0) {
            f32x4 z = {0.f, 0.f, 0.f, 0.f};
            *(f32x4*)(out + (size_t)row * N_DIM + t * TCOLS + tid * 4) = z;
        }
    }

    // ---- conversion: 16 elems/thread ----
    int idx = bid * 256 + tid;                 // 0 .. 2M-1
    const int n16 = M_DIM * K_DIM / 16;        // 1M threads per array
    u8x16 o;
    if (idx < n16) {
        const f32x4* s = (const f32x4*)x + (size_t)idx * 4;
        f32x4 a0 = s[0], a1 = s[1], a2 = s[2], a3 = s[3];
#pragma unroll
        for (int j = 0; j < 4; ++j) o[j]      = q8(a0[j]);
#pragma unroll
        for (int j = 0; j < 4; ++j) o[4 + j]  = q8(a1[j]);
#pragma unroll
        for (int j = 0; j < 4; ++j) o[8 + j]  = q8(a2[j]);
#pragma unroll
        for (int j = 0; j < 4; ++j) o[12 + j] = q8(a3[j]);
        *(u8x16*)(xq + (size_t)idx * 16) = o;
    } else {
        idx -= n16;
        const f32x4* s = (const f32x4*)w + (size_t)idx * 4;
        f32x4 a0 = s[0], a1 = s[1], a2 = s[2], a3 = s[3];
#pragma unroll
        for (int j = 0; j < 4; ++j) o[j]      = s8(a0[j]);
#pragma unroll
        for (int j = 0; j < 4; ++j) o[4 + j]  = s8(a1[j]);
#pragma unroll
        for (int j = 0; j < 4; ++j) o[8 + j]  = s8(a2[j]);
#pragma unroll
        for (int j = 0; j < 4; ++j) o[12 + j] = s8(a3[j]);
        *(u8x16*)(wq + (size_t)idx * 16) = o;
    }
}

// ---------------- async global->LDS, 16B per lane ----------------
__device__ __forceinline__ void gload_lds16(const int8_t* g, int8_t* l) {
    __builtin_amdgcn_global_load_lds(
        (__attribute__((address_space(1))) void*)(g),
        (__attribute__((address_space(3))) void*)(l),
        16, 0, 0);
}

// ---------------- i8 GEMM over the COMPACTED row domain ----------------
__global__ __launch_bounds__(256, 2) void trix_gemm(
    const int8_t* __restrict__ A,        // xq i8 [4096][4096]
    const int8_t* __restrict__ B,        // wq i8 [4096][4096] (O-major, K contig)
    const int* __restrict__ gate,        // [4096][4]
    const float* __restrict__ scales,    // [4096]
    const int* __restrict__ rowlist,     // [4][4096] compacted row ids
    const int* __restrict__ counts,      // [4]
    float* __restrict__ out)             // [4096][4096] fp32
{
    const int tile = blockIdx.x >> 3;         // 8 n-blocks per gate tile
    const int cnt  = counts[tile];
    const int m0   = blockIdx.y * BM;         // position in compacted domain
    if (m0 >= cnt) return;

    __shared__ __align__(16) int8_t As[BM * BKB];   // 16 KB
    __shared__ __align__(16) int8_t Bs[BN * BKB];   // 16 KB

    const int tid  = threadIdx.x;
    const int lane = tid & 63;
    const int wave = tid >> 6;       // 0..3
    const int wm   = wave >> 1;      // 0..1
    const int wn   = wave & 1;       // 0..1
    const int quad = lane >> 4;      // 0..3
    const int ln16 = lane & 15;

    const int n0 = blockIdx.x * BN;
    const int* rl = rowlist + tile * M_DIM;

    // ---- staging: 4 issues each for A and B per K-tile (1 KB per issue) ----
    const int srow   = lane >> 3;              // 0..7
    const int gchunk = (lane & 7) ^ srow;      // XOR swizzle in GLOBAL address
    const int8_t* a_src[4];
    const int8_t* b_src[4];
    int8_t* a_dst[4];
    int8_t* b_dst[4];
#pragma unroll
    for (int j = 0; j < 4; ++j) {
        int cidx = j * 4 + wave;
        int ra = m0 + cidx * 8 + srow;
        if (ra >= cnt) ra = cnt - 1;           // clamp surplus rows
        int grow = rl[ra];
        a_src[j] = A + (size_t)grow * K_DIM + gchunk * 16;
        b_src[j] = B + (size_t)(n0 + cidx * 8 + srow) * K_DIM + gchunk * 16;
        a_dst[j] = As + cidx * 1024;   // 8 rows x 128 B; HW adds lane*16B
        b_dst[j] = Bs + cidx * 1024;
    }

    // ---- fragment read addresses: lane reads 16 i8 at row, k = quad*16 + kk*64 ----
    const int8_t* a_rd[4][2];
    const int8_t* b_rd[4][2];
#pragma unroll
    for (int i = 0; i < 4; ++i) {
        int arow = wm * 64 + i * 16 + ln16;
        int brow = wn * 64 + i * 16 + ln16;
#pragma unroll
        for (int kk = 0; kk < 2; ++kk) {
            int ch = quad + 4 * kk;
            a_rd[i][kk] = As + arow * 128 + ((ch ^ (arow & 7)) * 16);
            b_rd[i][kk] = Bs + brow * 128 + ((ch ^ (brow & 7)) * 16);
        }
    }

    int4v acc[4][4];
#pragma unroll
    for (int i = 0; i < 4; ++i)
#pragma unroll
        for (int j = 0; j < 4; ++j)
            acc[i][j] = (int4v){0, 0, 0, 0};

    for (int kt = 0; kt < K_DIM; kt += BKB) {   // 32 tiles
#pragma unroll
        for (int j = 0; j < 4; ++j) {
            gload_lds16(a_src[j], a_dst[j]);
            gload_lds16(b_src[j], b_dst[j]);
        }
#pragma unroll
        for (int j = 0; j < 4; ++j) { a_src[j] += BKB; b_src[j] += BKB; }
        __syncthreads();

#pragma unroll
        for (int kk = 0; kk < 2; ++kk) {
            int4v af[4], bf[4];
#pragma unroll
            for (int i = 0; i < 4; ++i) af[i] = *(const int4v*)a_rd[i][kk];
#pragma unroll
            for (int i = 0; i < 4; ++i) bf[i] = *(const int4v*)b_rd[i][kk];
#pragma unroll
            for (int i = 0; i < 4; ++i)
#pragma unroll
                for (int j = 0; j < 4; ++j)
                    acc[i][j] = __builtin_amdgcn_mfma_i32_16x16x64_i8(
                        af[i], bf[j], acc[i][j], 0, 0, 0);
        }
        __syncthreads();
    }

    // ---- epilogue: out[grow] = acc_i32 * dq * scales[n] * gate[grow][tile] ----
    float sc[4];
#pragma unroll
    for (int j = 0; j < 4; ++j) sc[j] = scales[n0 + wn * 64 + j * 16 + ln16] * XDEQ;

#pragma unroll
    for (int i = 0; i < 4; ++i) {
        int lbase = wm * 64 + i * 16 + quad * 4;
#pragma unroll
        for (int r = 0; r < 4; ++r) {
            int lr = lbase + r;
            if (m0 + lr < cnt) {
                int grow = rl[m0 + lr];
                float g = (float)gate[grow * NT + tile];   // generality: gate may be >1
                float* orow = out + (size_t)grow * N_DIM + n0 + wn * 64 + ln16;
#pragma unroll
                for (int j = 0; j < 4; ++j)
                    orow[j * 16] = (float)acc[i][j][r] * sc[j] * g;
            }
        }
    }
}

extern "C" void kernel_launch(void* const* d_in, const int* in_sizes, int n_in,
                              void* d_out, int out_size, void* d_ws, size_t ws_size,
                              hipStream_t stream) {
    const float* x      = (const float*)d_in[0];   // [4096][4096]
    const int*   gate   = (const int*)d_in[1];     // [4096][4]
    const float* weight = (const float*)d_in[2];   // [4096][4096]
    const float* scales = (const float*)d_in[3];   // [4096]
    float* out = (float*)d_out;

    int8_t* xq = (int8_t*)d_ws;                           // 16 MB i8 x
    int8_t* wq = xq + (size_t)M_DIM * K_DIM;              // 16 MB i8 W
    int* rowlist = (int*)(wq + (size_t)N_DIM * K_DIM);    // 64 KB: 4 x 4096 row ids
    int* counts  = rowlist + NT * M_DIM;                  // 16 B

    // one dispatch: convert + zero-fill + compact (tail blocks)
    cvt_i8_kernel<<<NCVT + NT, 256, 0, stream>>>(x, weight, xq, wq,
                                                 gate, out, rowlist, counts);

    dim3 grid(N_DIM / BN, M_DIM / BM);                    // 32 x 32; ~half exit early
    trix_gemm<<<grid, 256, 0, stream>>>(xq, wq, gate, scales, rowlist, counts, out);
}